// Round 15
// baseline (100.876 us; speedup 1.0000x reference)
//
#include <hip/hip_runtime.h>
#include <math.h>

#define HH 256
#define WW 256
#define VV 192
#define DD 256

// geometry (matches reference linspace(-sqrt2,sqrt2,256), DT = 2*sqrt2/256)
#define DSQ2      1.41421356237309504880
#define F_DT      ((float)(2.0 * DSQ2 / 256.0))
#define F_INV_DS  ((float)(255.0 / (2.0 * DSQ2)))        // 90.1562 index per world unit
#define F_SIG     ((float)(256.0 * DSQ2 / 255.0))        // 1.41976 px per index step
#define F_RAD     ((float)(128.0 * DSQ2))                // 181.0193

#define TPITCH 67        // 66 used cols + 1 pad
#define TROWS  67        // 66 data rows + 1 zeroed safety row
#define NSEG 16
#define NV (VV / NSEG)   // 12 views per bwd segment -> 12.3 KB LDS -> 8 blocks/CU
#define VG 3             // 16*64*2 = 2048 blocks = exactly one resident batch (8/CU)

static __device__ __forceinline__ float view_angle(int v) {
    // matches np.linspace(0, pi, 192, endpoint=False): f64 mul then cast
    return (float)((double)v * (3.14159265358979323846 / 192.0));
}

// t-interval of { t : lo <= L + t*step < hi } (robust to step ~ 0)
static __device__ __forceinline__ void axis_interval(float L, float lo, float hi,
                                                     float step, float& a, float& b) {
    if (fabsf(step) > 1e-5f) {
        const float r = 1.0f / step;
        const float u = (lo - L) * r;
        const float w = (hi - L) * r;
        a = fminf(u, w);
        b = fmaxf(u, w);
    } else {
        const bool in = (L >= lo) && (L < hi);
        a = in ? -1e9f : 1e9f;
        b = in ?  1e9f : -1e9f;
    }
}

// ---------------------------------------------------------------------------
// Kernel 0: out = input ; sacc = 0
// ---------------------------------------------------------------------------
__global__ __launch_bounds__(256)
void init_kernel(const float* __restrict__ input,
                 float* __restrict__ out,
                 float* __restrict__ sacc,
                 int npix4, int nsino4) {
    const int stride = gridDim.x * 256;
    const float4* in4 = (const float4*)input;
    float4* o4 = (float4*)out;
    float4* s4 = (float4*)sacc;
    for (int i = blockIdx.x * 256 + threadIdx.x; i < npix4; i += stride)
        o4[i] = in4[i];
    for (int i = blockIdx.x * 256 + threadIdx.x; i < nsino4; i += stride)
        s4[i] = make_float4(0.f, 0.f, 0.f, 0.f);
}

// ---------------------------------------------------------------------------
// Kernel 1: tile-local sample-driven forward projection (r14 structure).
// Block = (64x64 tile, VG views, image). Waves own 16-d bands (lane = 16 d x
// 4 t-phases); per-lane exact t-intervals; shfl_xor phase reduction;
// <=64 guarded atomics per (view, dbase). VG=3 -> 2048 blocks, zero tail.
// ---------------------------------------------------------------------------
__global__ __launch_bounds__(256)
void fwd_tile_kernel(const float* __restrict__ img_all,
                     float* __restrict__ sacc) {
    __shared__ float tile[TROWS * TPITCH];
    const int tx = (blockIdx.x & 3) << 6;
    const int ty = (blockIdx.x >> 2) << 6;
    const int v0 = blockIdx.y * VG;
    const int b  = blockIdx.z;
    const int tid  = threadIdx.x;
    const int lane = tid & 63;
    const int wv   = tid >> 6;
    const int doff = lane & 15;          // d within the wave's 16-wide band
    const int ph   = lane >> 4;          // t phase 0..3

    const float* __restrict__ img = img_all + (b << 16);

    // ---- stage 66x66 (x,y in [tx-1,tx+64] x [ty-1,ty+64], 0 outside) ----
    for (int k = tid; k < 64 * 16; k += 256) {           // interior, float4
        const int r  = k >> 4;
        const int c4 = (k & 15) << 2;
        const float4 val = *(const float4*)(img + ((ty + r) << 8) + tx + c4);
        float* dst = tile + (r + 1) * TPITCH + 1 + c4;
        dst[0] = val.x; dst[1] = val.y; dst[2] = val.z; dst[3] = val.w;
    }
    if (tid < 132) {                                     // vertical halo cols (0, 65)
        const int r  = tid >> 1;
        const int cc = (tid & 1) ? 65 : 0;
        const int gx = tx - 1 + cc;
        const int gy = ty - 1 + r;
        float vv = 0.0f;
        if ((unsigned)gx < 256u && (unsigned)gy < 256u) vv = img[(gy << 8) + gx];
        tile[r * TPITCH + cc] = vv;
    }
    if (tid < 128) {                                     // horizontal halo rows (0, 65)
        const int cc = 1 + (tid & 63);
        const int r  = (tid >> 6) ? 65 : 0;
        const int gx = tx - 1 + cc;
        const int gy = ty - 1 + r;
        float vv = 0.0f;
        if ((unsigned)gx < 256u && (unsigned)gy < 256u) vv = img[(gy << 8) + gx];
        tile[r * TPITCH + cc] = vv;
    }
    if (tid < TPITCH) tile[66 * TPITCH + tid] = 0.0f;    // safety row

    // ownership bounds (constant across views)
    const int lox = (tx == 0) ? -1 : 0;
    const int loy = (ty == 0) ? -1 : 0;
    const unsigned spanx = (unsigned)(64 - lox);
    const unsigned spany = (unsigned)(64 - loy);
    const float txl = (float)(tx + lox), txh = (float)(tx + 64);
    const float tyl = (float)(ty + loy), tyh = (float)(ty + 64);
    const float xwl = (txl + 0.5f) * (1.0f / 128.0f) - 1.0f;
    const float xwh = (txh + 0.5f) * (1.0f / 128.0f) - 1.0f;
    const float ywl = (tyl + 0.5f) * (1.0f / 128.0f) - 1.0f;
    const float ywh = (tyh + 0.5f) * (1.0f / 128.0f) - 1.0f;

    __syncthreads();

    for (int vg = 0; vg < VG; ++vg) {
        const int v = v0 + vg;
        float sn, cs;
        sincosf(view_angle(v), &sn, &cs);
        const float Xd = -sn * F_SIG, Yd = cs * F_SIG;
        const float Xt =  cs * F_SIG, Yt = sn * F_SIG;
        const float X0 = 127.5f - F_RAD * (cs - sn);
        const float Y0 = 127.5f - F_RAD * (cs + sn);

        // (d,t) bbox (for dbase loop and clamping)
        const float dA = -xwl * sn, dB = -xwh * sn;
        const float dC =  ywl * cs, dDq =  ywh * cs;
        const float tAq =  xwl * cs, tB =  xwh * cs;
        const float tC =  ywl * sn, tD =  ywh * sn;
        const float dcmin = 127.5f + (fminf(dA, dB) + fminf(dC, dDq)) * F_INV_DS;
        const float dcmax = 127.5f + (fmaxf(dA, dB) + fmaxf(dC, dDq)) * F_INV_DS;
        const float tcmin = 127.5f + (fminf(tAq, tB) + fminf(tC, tD)) * F_INV_DS;
        const float tcmax = 127.5f + (fmaxf(tAq, tB) + fmaxf(tC, tD)) * F_INV_DS;
        const int dlo = max(0, (int)ceilf(dcmin - 0.002f));
        const int dhi = min(255, (int)floorf(dcmax + 0.002f));
        const int tlo = max(0, (int)ceilf(tcmin - 0.002f));
        const int thi = min(255, (int)floorf(tcmax + 0.002f));

        const int sbase = (b * VV + v) << 8;
        for (int dbase = dlo; dbase <= dhi; dbase += 64) {
            const int d = dbase + (wv << 4) + doff;
            const float xLg = fmaf((float)d, Xd, X0);     // pixel coords at t=0
            const float yLg = fmaf((float)d, Yd, Y0);

            // per-lane exact t-interval = intersection of two strips
            float ax, bx, ay, by;
            axis_interval(xLg, txl, txh, Xt, ax, bx);
            axis_interval(yLg, tyl, tyh, Yt, ay, by);
            const float tminf = fmaxf(ax, ay);
            const float tmaxf = fminf(bx, by);
            const float tbf = fminf(fmaxf(tminf - 0.002f, (float)tlo), 300.0f);
            const float tef = fmaxf(fminf(tmaxf + 0.002f, (float)thi), -2.0f);
            int tb = (int)ceilf(tbf);
            const int te = (int)floorf(tef);
            tb += (ph - tb) & 3;                          // align to this lane's phase

            float acc = 0.0f;
            float xc = fmaf((float)tb, Xt, xLg) - (float)tx + 1.0f;
            float yc = fmaf((float)tb, Yt, yLg) - (float)ty + 1.0f;
            const float sx = 4.0f * Xt, sy = 4.0f * Yt;
#pragma unroll 2
            for (int t = tb; t <= te; t += 4) {
                const float xf = floorf(xc);
                const float yf = floorf(yc);
                const int cx = (int)xf;
                const int cy = (int)yf;
                const float fx = xc - xf;
                const float fy = yc - yf;
                const bool ok = (((unsigned)(cx - 1 - lox) < spanx) &
                                 ((unsigned)(cy - 1 - loy) < spany));
                const int a0 = max(cy * TPITCH + cx, 0);  // interval => in-bounds skin
                const float v00 = tile[a0],          v10 = tile[a0 + 1];
                const float v01 = tile[a0 + TPITCH], v11 = tile[a0 + TPITCH + 1];
                const float top = fmaf(fx, v10 - v00, v00);
                const float bot = fmaf(fx, v11 - v01, v01);
                const float smp = fmaf(fy, bot - top, top);
                acc += ok ? smp : 0.0f;
                xc += sx; yc += sy;
            }
            // reduce the 4 t-phases holding the same d (lanes xor 16, 32)
            acc += __shfl_xor(acc, 16, 64);
            acc += __shfl_xor(acc, 32, 64);
            if (ph == 0 && acc != 0.0f && d <= dhi)
                atomicAdd(sacc + sbase + d, acc);
        }
        // tile is read-only across views: no barrier needed
    }
}

// ---------------------------------------------------------------------------
// Kernel 2: pixel-driven exact adjoint (r9 verbatim, scalar): LDS-staged view
// segment, 2 px/thread, weight folded, atomicAdd into out.
// ---------------------------------------------------------------------------
__global__ __launch_bounds__(256, 8)
void bwd_partial_kernel(const float* __restrict__ sacc,
                        const float* __restrict__ proj,
                        const float* __restrict__ weight,
                        float* __restrict__ out) {
    __shared__ float s_t[NV * DD];
    __shared__ float4 s_g[NV];
    const int tid = threadIdx.x;
    const int v0 = blockIdx.y * NV;
    const int b  = (int)blockIdx.x >> 7;          // 128 blocks (512 px) per image

    if (tid < NV) {
        float sn, cs;
        sincosf(view_angle(v0 + tid), &sn, &cs);
        s_g[tid] = make_float4(cs, sn, F_SIG * cs, F_SIG * sn);
    }
    {   // stage s_t = DT*sacc - proj : NV*DD/4 = 768 float4 chunks
        const int base = (b * VV + v0) << 8;
        const float4* s4 = (const float4*)(sacc + base);
        const float4* p4 = (const float4*)(proj + base);
#pragma unroll
        for (int k = 0; k < NV * (DD / 4) / 256; ++k) {
            const int i = tid + (k << 8);
            const float4 a = s4[i];
            const float4 p = p4[i];
            float4 r;
            r.x = fmaf(F_DT, a.x, -p.x);
            r.y = fmaf(F_DT, a.y, -p.y);
            r.z = fmaf(F_DT, a.z, -p.z);
            r.w = fmaf(F_DT, a.w, -p.w);
            ((float4*)s_t)[i] = r;
        }
    }
    __syncthreads();

    const int idx = ((int)blockIdx.x << 9) + tid;     // pixel 0; pixel 1 = idx+256
    const int y0 = (idx >> 8) & 255;
    const int x  = idx & 255;
    const float xw  = (float)x  * (1.0f / 128.0f) + (0.5f / 128.0f - 1.0f);
    const float yw0 = (float)y0 * (1.0f / 128.0f) + (0.5f / 128.0f - 1.0f);
    const float yw1 = yw0 + (1.0f / 128.0f);

    float acc0 = 0.0f, acc1 = 0.0f;
#pragma unroll 2
    for (int vi = 0; vi < NV; ++vi) {
        const float4 g = s_g[vi];                 // cs, sn, A=sig*cs, B=sig*sn
        const float* __restrict__ row = s_t + (vi << 8);
#pragma unroll
        for (int p = 0; p < 2; ++p) {
            const float yw = p ? yw1 : yw0;
            const float sw = fmaf(-xw, g.y, yw * g.x);
            const float tw = fmaf( xw, g.x, yw * g.y);
            const float dc = fmaf(sw, F_INV_DS, 127.5f);
            const float tc = fmaf(tw, F_INV_DS, 127.5f);
            const float d0f = floorf(dc);
            const float t0f = floorf(tc);
            const int d0 = (int)d0f;
            const float fd = dc - d0f;
            const float ft = tc - t0f;

            const float dx00 = fmaf(g.z, -ft, g.w * fd);
            const float dyn  = fmaf(g.z,  fd, g.w * ft);
            const float dx01 = dx00 + g.z;
            const float dy01 = g.w - dyn;
            const float dx10 = dx00 - g.w;
            const float dy10 = g.z - dyn;
            const float dx11 = dx01 - g.w;
            const float dy11 = dy10 + g.w;

            const float w00 = fmaxf(0.0f, 1.0f - fabsf(dx00)) * fmaxf(0.0f, 1.0f - fabsf(dyn));
            const float w01 = fmaxf(0.0f, 1.0f - fabsf(dx01)) * fmaxf(0.0f, 1.0f - fabsf(dy01));
            const float w10 = fmaxf(0.0f, 1.0f - fabsf(dx10)) * fmaxf(0.0f, 1.0f - fabsf(dy10));
            const float w11 = fmaxf(0.0f, 1.0f - fabsf(dx11)) * fmaxf(0.0f, 1.0f - fabsf(dy11));

            const float rA = row[d0];
            const float rB = row[d0 + 1];
            if (p == 0) {
                acc0 = fmaf(w00 + w01, rA, acc0);
                acc0 = fmaf(w10 + w11, rB, acc0);
            } else {
                acc1 = fmaf(w00 + w01, rA, acc1);
                acc1 = fmaf(w10 + w11, rB, acc1);
            }
        }
    }

    const float c = -weight[0] * F_DT;
    atomicAdd(out + idx, c * acc0);
    atomicAdd(out + idx + 256, c * acc1);
}

extern "C" void kernel_launch(void* const* d_in, const int* in_sizes, int n_in,
                              void* d_out, int out_size, void* d_ws, size_t ws_size,
                              hipStream_t stream) {
    const float* input  = (const float*)d_in[0];   // [nb, H, W]
    const float* proj   = (const float*)d_in[1];   // [nb, V, D]
    const float* weight = (const float*)d_in[2];   // [1]
    float* out  = (float*)d_out;                   // [nb, H, W]
    float* sacc = (float*)d_ws;                    // [nb, V, D] forward accumulator

    const int nb = in_sizes[0] / (HH * WW);        // B*C = 2
    const int npix = nb * HH * WW;

    init_kernel<<<256, 256, 0, stream>>>(input, out, sacc, npix / 4, nb * VV * DD / 4);
    fwd_tile_kernel<<<dim3(16, VV / VG, nb), 256, 0, stream>>>(input, sacc);
    bwd_partial_kernel<<<dim3(npix / 512, NSEG), 256, 0, stream>>>(sacc, proj, weight, out);
}

// Round 16
// 100.563 us; speedup vs baseline: 1.0031x; 1.0031x over previous
//
#include <hip/hip_runtime.h>
#include <math.h>

#define HH 256
#define WW 256
#define VV 192
#define DD 256

// geometry (matches reference linspace(-sqrt2,sqrt2,256), DT = 2*sqrt2/256)
#define DSQ2      1.41421356237309504880
#define F_DT      ((float)(2.0 * DSQ2 / 256.0))
#define F_INV_DS  ((float)(255.0 / (2.0 * DSQ2)))        // 90.1562 index per world unit
#define F_SIG     ((float)(256.0 * DSQ2 / 255.0))        // 1.41976 px per index step
#define F_RAD     ((float)(128.0 * DSQ2))                // 181.0193

#define TPITCH 67        // 66 used cols + 1 pad
#define TROWS  67        // 66 data rows + 1 zeroed safety row
#define NSEG 16
#define NV (VV / NSEG)   // 12 views per bwd segment -> 12.3 KB LDS -> 8 blocks/CU
#define VG 2             // best-known (r14): 3072 blocks

static __device__ __forceinline__ float view_angle(int v) {
    // matches np.linspace(0, pi, 192, endpoint=False): f64 mul then cast
    return (float)((double)v * (3.14159265358979323846 / 192.0));
}

// t-interval of { t : lo <= L + t*step < hi } (robust to step ~ 0)
static __device__ __forceinline__ void axis_interval(float L, float lo, float hi,
                                                     float step, float& a, float& b) {
    if (fabsf(step) > 1e-5f) {
        const float r = 1.0f / step;
        const float u = (lo - L) * r;
        const float w = (hi - L) * r;
        a = fminf(u, w);
        b = fmaxf(u, w);
    } else {
        const bool in = (L >= lo) && (L < hi);
        a = in ? -1e9f : 1e9f;
        b = in ?  1e9f : -1e9f;
    }
}

// ---------------------------------------------------------------------------
// Kernel 0: out = input ; sacc = 0
// ---------------------------------------------------------------------------
__global__ __launch_bounds__(256)
void init_kernel(const float* __restrict__ input,
                 float* __restrict__ out,
                 float* __restrict__ sacc,
                 int npix4, int nsino4) {
    const int stride = gridDim.x * 256;
    const float4* in4 = (const float4*)input;
    float4* o4 = (float4*)out;
    float4* s4 = (float4*)sacc;
    for (int i = blockIdx.x * 256 + threadIdx.x; i < npix4; i += stride)
        o4[i] = in4[i];
    for (int i = blockIdx.x * 256 + threadIdx.x; i < nsino4; i += stride)
        s4[i] = make_float4(0.f, 0.f, 0.f, 0.f);
}

// ---------------------------------------------------------------------------
// Kernel 1: tile-local sample-driven forward projection (r14 structure).
// Block = (64x64 tile, VG views, image). Waves own 16-d bands (lane = 16 d x
// 4 t-phases); per-lane exact t-intervals; shfl_xor phase reduction.
// CHANGE vs r14: inner-loop addresses computed independently per trip
// (no float induction chain) so unroll-4's 16 ds_reads can all be in flight.
// ---------------------------------------------------------------------------
__global__ __launch_bounds__(256)
void fwd_tile_kernel(const float* __restrict__ img_all,
                     float* __restrict__ sacc) {
    __shared__ float tile[TROWS * TPITCH];
    const int tx = (blockIdx.x & 3) << 6;
    const int ty = (blockIdx.x >> 2) << 6;
    const int v0 = blockIdx.y * VG;
    const int b  = blockIdx.z;
    const int tid  = threadIdx.x;
    const int lane = tid & 63;
    const int wv   = tid >> 6;
    const int doff = lane & 15;          // d within the wave's 16-wide band
    const int ph   = lane >> 4;          // t phase 0..3

    const float* __restrict__ img = img_all + (b << 16);

    // ---- stage 66x66 (x,y in [tx-1,tx+64] x [ty-1,ty+64], 0 outside) ----
    for (int k = tid; k < 64 * 16; k += 256) {           // interior, float4
        const int r  = k >> 4;
        const int c4 = (k & 15) << 2;
        const float4 val = *(const float4*)(img + ((ty + r) << 8) + tx + c4);
        float* dst = tile + (r + 1) * TPITCH + 1 + c4;
        dst[0] = val.x; dst[1] = val.y; dst[2] = val.z; dst[3] = val.w;
    }
    if (tid < 132) {                                     // vertical halo cols (0, 65)
        const int r  = tid >> 1;
        const int cc = (tid & 1) ? 65 : 0;
        const int gx = tx - 1 + cc;
        const int gy = ty - 1 + r;
        float vv = 0.0f;
        if ((unsigned)gx < 256u && (unsigned)gy < 256u) vv = img[(gy << 8) + gx];
        tile[r * TPITCH + cc] = vv;
    }
    if (tid < 128) {                                     // horizontal halo rows (0, 65)
        const int cc = 1 + (tid & 63);
        const int r  = (tid >> 6) ? 65 : 0;
        const int gx = tx - 1 + cc;
        const int gy = ty - 1 + r;
        float vv = 0.0f;
        if ((unsigned)gx < 256u && (unsigned)gy < 256u) vv = img[(gy << 8) + gx];
        tile[r * TPITCH + cc] = vv;
    }
    if (tid < TPITCH) tile[66 * TPITCH + tid] = 0.0f;    // safety row

    // ownership bounds (constant across views)
    const int lox = (tx == 0) ? -1 : 0;
    const int loy = (ty == 0) ? -1 : 0;
    const unsigned spanx = (unsigned)(64 - lox);
    const unsigned spany = (unsigned)(64 - loy);
    const float txl = (float)(tx + lox), txh = (float)(tx + 64);
    const float tyl = (float)(ty + loy), tyh = (float)(ty + 64);
    const float xwl = (txl + 0.5f) * (1.0f / 128.0f) - 1.0f;
    const float xwh = (txh + 0.5f) * (1.0f / 128.0f) - 1.0f;
    const float ywl = (tyl + 0.5f) * (1.0f / 128.0f) - 1.0f;
    const float ywh = (tyh + 0.5f) * (1.0f / 128.0f) - 1.0f;

    __syncthreads();

    for (int vg = 0; vg < VG; ++vg) {
        const int v = v0 + vg;
        float sn, cs;
        sincosf(view_angle(v), &sn, &cs);
        const float Xd = -sn * F_SIG, Yd = cs * F_SIG;
        const float Xt =  cs * F_SIG, Yt = sn * F_SIG;
        const float X0 = 127.5f - F_RAD * (cs - sn);
        const float Y0 = 127.5f - F_RAD * (cs + sn);

        // (d,t) bbox (for dbase loop and clamping)
        const float dA = -xwl * sn, dB = -xwh * sn;
        const float dC =  ywl * cs, dDq =  ywh * cs;
        const float tAq =  xwl * cs, tB =  xwh * cs;
        const float tC =  ywl * sn, tD =  ywh * sn;
        const float dcmin = 127.5f + (fminf(dA, dB) + fminf(dC, dDq)) * F_INV_DS;
        const float dcmax = 127.5f + (fmaxf(dA, dB) + fmaxf(dC, dDq)) * F_INV_DS;
        const float tcmin = 127.5f + (fminf(tAq, tB) + fminf(tC, tD)) * F_INV_DS;
        const float tcmax = 127.5f + (fmaxf(tAq, tB) + fmaxf(tC, tD)) * F_INV_DS;
        const int dlo = max(0, (int)ceilf(dcmin - 0.002f));
        const int dhi = min(255, (int)floorf(dcmax + 0.002f));
        const int tlo = max(0, (int)ceilf(tcmin - 0.002f));
        const int thi = min(255, (int)floorf(tcmax + 0.002f));

        const int sbase = (b * VV + v) << 8;
        for (int dbase = dlo; dbase <= dhi; dbase += 64) {
            const int d = dbase + (wv << 4) + doff;
            const float xLg = fmaf((float)d, Xd, X0);     // pixel coords at t=0
            const float yLg = fmaf((float)d, Yd, Y0);

            // per-lane exact t-interval = intersection of two strips
            float ax, bx, ay, by;
            axis_interval(xLg, txl, txh, Xt, ax, bx);
            axis_interval(yLg, tyl, tyh, Yt, ay, by);
            const float tminf = fmaxf(ax, ay);
            const float tmaxf = fminf(bx, by);
            const float tbf = fminf(fmaxf(tminf - 0.002f, (float)tlo), 300.0f);
            const float tef = fmaxf(fminf(tmaxf + 0.002f, (float)thi), -2.0f);
            int tb = (int)ceilf(tbf);
            const int te = (int)floorf(tef);
            tb += (ph - tb) & 3;                          // align to this lane's phase

            float acc = 0.0f;
            // base position at t=tb; each trip's coords derived INDEPENDENTLY
            const float xb = fmaf((float)tb, Xt, xLg) - (float)tx + 1.0f;
            const float yb = fmaf((float)tb, Yt, yLg) - (float)ty + 1.0f;
#pragma unroll 4
            for (int t = tb; t <= te; t += 4) {
                const float j  = (float)(t - tb);         // exact small int
                const float xc = fmaf(j, Xt, xb);
                const float yc = fmaf(j, Yt, yb);
                const float xf = floorf(xc);
                const float yf = floorf(yc);
                const int cx = (int)xf;
                const int cy = (int)yf;
                const float fx = xc - xf;
                const float fy = yc - yf;
                const bool ok = (((unsigned)(cx - 1 - lox) < spanx) &
                                 ((unsigned)(cy - 1 - loy) < spany));
                const int a0 = max(cy * TPITCH + cx, 0);  // interval => in-bounds skin
                const float v00 = tile[a0],          v10 = tile[a0 + 1];
                const float v01 = tile[a0 + TPITCH], v11 = tile[a0 + TPITCH + 1];
                const float top = fmaf(fx, v10 - v00, v00);
                const float bot = fmaf(fx, v11 - v01, v01);
                const float smp = fmaf(fy, bot - top, top);
                acc += ok ? smp : 0.0f;
            }
            // reduce the 4 t-phases holding the same d (lanes xor 16, 32)
            acc += __shfl_xor(acc, 16, 64);
            acc += __shfl_xor(acc, 32, 64);
            if (ph == 0 && acc != 0.0f && d <= dhi)
                atomicAdd(sacc + sbase + d, acc);
        }
        // tile is read-only across views: no barrier needed
    }
}

// ---------------------------------------------------------------------------
// Kernel 2: pixel-driven exact adjoint (r9/r14 verbatim): LDS-staged view
// segment, 2 px/thread, weight folded, atomicAdd into out.
// ---------------------------------------------------------------------------
__global__ __launch_bounds__(256, 8)
void bwd_partial_kernel(const float* __restrict__ sacc,
                        const float* __restrict__ proj,
                        const float* __restrict__ weight,
                        float* __restrict__ out) {
    __shared__ float s_t[NV * DD];
    __shared__ float4 s_g[NV];
    const int tid = threadIdx.x;
    const int v0 = blockIdx.y * NV;
    const int b  = (int)blockIdx.x >> 7;          // 128 blocks (512 px) per image

    if (tid < NV) {
        float sn, cs;
        sincosf(view_angle(v0 + tid), &sn, &cs);
        s_g[tid] = make_float4(cs, sn, F_SIG * cs, F_SIG * sn);
    }
    {   // stage s_t = DT*sacc - proj : NV*DD/4 = 768 float4 chunks
        const int base = (b * VV + v0) << 8;
        const float4* s4 = (const float4*)(sacc + base);
        const float4* p4 = (const float4*)(proj + base);
#pragma unroll
        for (int k = 0; k < NV * (DD / 4) / 256; ++k) {
            const int i = tid + (k << 8);
            const float4 a = s4[i];
            const float4 p = p4[i];
            float4 r;
            r.x = fmaf(F_DT, a.x, -p.x);
            r.y = fmaf(F_DT, a.y, -p.y);
            r.z = fmaf(F_DT, a.z, -p.z);
            r.w = fmaf(F_DT, a.w, -p.w);
            ((float4*)s_t)[i] = r;
        }
    }
    __syncthreads();

    const int idx = ((int)blockIdx.x << 9) + tid;     // pixel 0; pixel 1 = idx+256
    const int y0 = (idx >> 8) & 255;
    const int x  = idx & 255;
    const float xw  = (float)x  * (1.0f / 128.0f) + (0.5f / 128.0f - 1.0f);
    const float yw0 = (float)y0 * (1.0f / 128.0f) + (0.5f / 128.0f - 1.0f);
    const float yw1 = yw0 + (1.0f / 128.0f);

    float acc0 = 0.0f, acc1 = 0.0f;
#pragma unroll 2
    for (int vi = 0; vi < NV; ++vi) {
        const float4 g = s_g[vi];                 // cs, sn, A=sig*cs, B=sig*sn
        const float* __restrict__ row = s_t + (vi << 8);
#pragma unroll
        for (int p = 0; p < 2; ++p) {
            const float yw = p ? yw1 : yw0;
            const float sw = fmaf(-xw, g.y, yw * g.x);
            const float tw = fmaf( xw, g.x, yw * g.y);
            const float dc = fmaf(sw, F_INV_DS, 127.5f);
            const float tc = fmaf(tw, F_INV_DS, 127.5f);
            const float d0f = floorf(dc);
            const float t0f = floorf(tc);
            const int d0 = (int)d0f;
            const float fd = dc - d0f;
            const float ft = tc - t0f;

            const float dx00 = fmaf(g.z, -ft, g.w * fd);
            const float dyn  = fmaf(g.z,  fd, g.w * ft);
            const float dx01 = dx00 + g.z;
            const float dy01 = g.w - dyn;
            const float dx10 = dx00 - g.w;
            const float dy10 = g.z - dyn;
            const float dx11 = dx01 - g.w;
            const float dy11 = dy10 + g.w;

            const float w00 = fmaxf(0.0f, 1.0f - fabsf(dx00)) * fmaxf(0.0f, 1.0f - fabsf(dyn));
            const float w01 = fmaxf(0.0f, 1.0f - fabsf(dx01)) * fmaxf(0.0f, 1.0f - fabsf(dy01));
            const float w10 = fmaxf(0.0f, 1.0f - fabsf(dx10)) * fmaxf(0.0f, 1.0f - fabsf(dy10));
            const float w11 = fmaxf(0.0f, 1.0f - fabsf(dx11)) * fmaxf(0.0f, 1.0f - fabsf(dy11));

            const float rA = row[d0];
            const float rB = row[d0 + 1];
            if (p == 0) {
                acc0 = fmaf(w00 + w01, rA, acc0);
                acc0 = fmaf(w10 + w11, rB, acc0);
            } else {
                acc1 = fmaf(w00 + w01, rA, acc1);
                acc1 = fmaf(w10 + w11, rB, acc1);
            }
        }
    }

    const float c = -weight[0] * F_DT;
    atomicAdd(out + idx, c * acc0);
    atomicAdd(out + idx + 256, c * acc1);
}

extern "C" void kernel_launch(void* const* d_in, const int* in_sizes, int n_in,
                              void* d_out, int out_size, void* d_ws, size_t ws_size,
                              hipStream_t stream) {
    const float* input  = (const float*)d_in[0];   // [nb, H, W]
    const float* proj   = (const float*)d_in[1];   // [nb, V, D]
    const float* weight = (const float*)d_in[2];   // [1]
    float* out  = (float*)d_out;                   // [nb, H, W]
    float* sacc = (float*)d_ws;                    // [nb, V, D] forward accumulator

    const int nb = in_sizes[0] / (HH * WW);        // B*C = 2
    const int npix = nb * HH * WW;

    init_kernel<<<256, 256, 0, stream>>>(input, out, sacc, npix / 4, nb * VV * DD / 4);
    fwd_tile_kernel<<<dim3(16, VV / VG, nb), 256, 0, stream>>>(input, sacc);
    bwd_partial_kernel<<<dim3(npix / 512, NSEG), 256, 0, stream>>>(sacc, proj, weight, out);
}

// Round 17
// 98.340 us; speedup vs baseline: 1.0258x; 1.0226x over previous
//
#include <hip/hip_runtime.h>
#include <math.h>

#define HH 256
#define WW 256
#define VV 192
#define DD 256

// geometry (matches reference linspace(-sqrt2,sqrt2,256), DT = 2*sqrt2/256)
#define DSQ2      1.41421356237309504880
#define F_DT      ((float)(2.0 * DSQ2 / 256.0))
#define F_INV_DS  ((float)(255.0 / (2.0 * DSQ2)))        // 90.1562 index per world unit
#define F_SIG     ((float)(256.0 * DSQ2 / 255.0))        // 1.41976 px per index step
#define F_RAD     ((float)(128.0 * DSQ2))                // 181.0193

#define TPITCH 67        // 66 used cols + 1 pad
#define TROWS  67        // 66 data rows + 1 zeroed safety row
#define NSEG 16
#define NV (VV / NSEG)   // 12 views per bwd segment -> 12.3 KB LDS -> 8 blocks/CU
#define VG 2             // best-measured (r14): 3072 blocks

static __device__ __forceinline__ float view_angle(int v) {
    // matches np.linspace(0, pi, 192, endpoint=False): f64 mul then cast
    return (float)((double)v * (3.14159265358979323846 / 192.0));
}

// t-interval of { t : lo <= L + t*step < hi } (robust to step ~ 0)
static __device__ __forceinline__ void axis_interval(float L, float lo, float hi,
                                                     float step, float& a, float& b) {
    if (fabsf(step) > 1e-5f) {
        const float r = 1.0f / step;
        const float u = (lo - L) * r;
        const float w = (hi - L) * r;
        a = fminf(u, w);
        b = fmaxf(u, w);
    } else {
        const bool in = (L >= lo) && (L < hi);
        a = in ? -1e9f : 1e9f;
        b = in ?  1e9f : -1e9f;
    }
}

// ---------------------------------------------------------------------------
// Kernel 0: out = input ; sacc = 0
// ---------------------------------------------------------------------------
__global__ __launch_bounds__(256)
void init_kernel(const float* __restrict__ input,
                 float* __restrict__ out,
                 float* __restrict__ sacc,
                 int npix4, int nsino4) {
    const int stride = gridDim.x * 256;
    const float4* in4 = (const float4*)input;
    float4* o4 = (float4*)out;
    float4* s4 = (float4*)sacc;
    for (int i = blockIdx.x * 256 + threadIdx.x; i < npix4; i += stride)
        o4[i] = in4[i];
    for (int i = blockIdx.x * 256 + threadIdx.x; i < nsino4; i += stride)
        s4[i] = make_float4(0.f, 0.f, 0.f, 0.f);
}

// ---------------------------------------------------------------------------
// Kernel 1: tile-local sample-driven forward projection (r14, best-measured).
// Block = (64x64 tile, VG views, image). Waves own 16-d bands (lane = 16 d x
// 4 t-phases); per-lane exact t-intervals (closed form) kill bbox enumeration
// waste; incremental coords; shfl_xor phase reduction; <=64 guarded atomics
// per (view, dbase).
// ---------------------------------------------------------------------------
__global__ __launch_bounds__(256)
void fwd_tile_kernel(const float* __restrict__ img_all,
                     float* __restrict__ sacc) {
    __shared__ float tile[TROWS * TPITCH];
    const int tx = (blockIdx.x & 3) << 6;
    const int ty = (blockIdx.x >> 2) << 6;
    const int v0 = blockIdx.y * VG;
    const int b  = blockIdx.z;
    const int tid  = threadIdx.x;
    const int lane = tid & 63;
    const int wv   = tid >> 6;
    const int doff = lane & 15;          // d within the wave's 16-wide band
    const int ph   = lane >> 4;          // t phase 0..3

    const float* __restrict__ img = img_all + (b << 16);

    // ---- stage 66x66 (x,y in [tx-1,tx+64] x [ty-1,ty+64], 0 outside) ----
    for (int k = tid; k < 64 * 16; k += 256) {           // interior, float4
        const int r  = k >> 4;
        const int c4 = (k & 15) << 2;
        const float4 val = *(const float4*)(img + ((ty + r) << 8) + tx + c4);
        float* dst = tile + (r + 1) * TPITCH + 1 + c4;
        dst[0] = val.x; dst[1] = val.y; dst[2] = val.z; dst[3] = val.w;
    }
    if (tid < 132) {                                     // vertical halo cols (0, 65)
        const int r  = tid >> 1;
        const int cc = (tid & 1) ? 65 : 0;
        const int gx = tx - 1 + cc;
        const int gy = ty - 1 + r;
        float vv = 0.0f;
        if ((unsigned)gx < 256u && (unsigned)gy < 256u) vv = img[(gy << 8) + gx];
        tile[r * TPITCH + cc] = vv;
    }
    if (tid < 128) {                                     // horizontal halo rows (0, 65)
        const int cc = 1 + (tid & 63);
        const int r  = (tid >> 6) ? 65 : 0;
        const int gx = tx - 1 + cc;
        const int gy = ty - 1 + r;
        float vv = 0.0f;
        if ((unsigned)gx < 256u && (unsigned)gy < 256u) vv = img[(gy << 8) + gx];
        tile[r * TPITCH + cc] = vv;
    }
    if (tid < TPITCH) tile[66 * TPITCH + tid] = 0.0f;    // safety row

    // ownership bounds (constant across views)
    const int lox = (tx == 0) ? -1 : 0;
    const int loy = (ty == 0) ? -1 : 0;
    const unsigned spanx = (unsigned)(64 - lox);
    const unsigned spany = (unsigned)(64 - loy);
    const float txl = (float)(tx + lox), txh = (float)(tx + 64);
    const float tyl = (float)(ty + loy), tyh = (float)(ty + 64);
    const float xwl = (txl + 0.5f) * (1.0f / 128.0f) - 1.0f;
    const float xwh = (txh + 0.5f) * (1.0f / 128.0f) - 1.0f;
    const float ywl = (tyl + 0.5f) * (1.0f / 128.0f) - 1.0f;
    const float ywh = (tyh + 0.5f) * (1.0f / 128.0f) - 1.0f;

    __syncthreads();

    for (int vg = 0; vg < VG; ++vg) {
        const int v = v0 + vg;
        float sn, cs;
        sincosf(view_angle(v), &sn, &cs);
        const float Xd = -sn * F_SIG, Yd = cs * F_SIG;
        const float Xt =  cs * F_SIG, Yt = sn * F_SIG;
        const float X0 = 127.5f - F_RAD * (cs - sn);
        const float Y0 = 127.5f - F_RAD * (cs + sn);

        // (d,t) bbox (for dbase loop and clamping)
        const float dA = -xwl * sn, dB = -xwh * sn;
        const float dC =  ywl * cs, dDq =  ywh * cs;
        const float tAq =  xwl * cs, tB =  xwh * cs;
        const float tC =  ywl * sn, tD =  ywh * sn;
        const float dcmin = 127.5f + (fminf(dA, dB) + fminf(dC, dDq)) * F_INV_DS;
        const float dcmax = 127.5f + (fmaxf(dA, dB) + fmaxf(dC, dDq)) * F_INV_DS;
        const float tcmin = 127.5f + (fminf(tAq, tB) + fminf(tC, tD)) * F_INV_DS;
        const float tcmax = 127.5f + (fmaxf(tAq, tB) + fmaxf(tC, tD)) * F_INV_DS;
        const int dlo = max(0, (int)ceilf(dcmin - 0.002f));
        const int dhi = min(255, (int)floorf(dcmax + 0.002f));
        const int tlo = max(0, (int)ceilf(tcmin - 0.002f));
        const int thi = min(255, (int)floorf(tcmax + 0.002f));

        const int sbase = (b * VV + v) << 8;
        for (int dbase = dlo; dbase <= dhi; dbase += 64) {
            const int d = dbase + (wv << 4) + doff;
            const float xLg = fmaf((float)d, Xd, X0);     // pixel coords at t=0
            const float yLg = fmaf((float)d, Yd, Y0);

            // per-lane exact t-interval = intersection of two strips
            float ax, bx, ay, by;
            axis_interval(xLg, txl, txh, Xt, ax, bx);
            axis_interval(yLg, tyl, tyh, Yt, ay, by);
            const float tminf = fmaxf(ax, ay);
            const float tmaxf = fminf(bx, by);
            const float tbf = fminf(fmaxf(tminf - 0.002f, (float)tlo), 300.0f);
            const float tef = fmaxf(fminf(tmaxf + 0.002f, (float)thi), -2.0f);
            int tb = (int)ceilf(tbf);
            const int te = (int)floorf(tef);
            tb += (ph - tb) & 3;                          // align to this lane's phase

            float acc = 0.0f;
            float xc = fmaf((float)tb, Xt, xLg) - (float)tx + 1.0f;
            float yc = fmaf((float)tb, Yt, yLg) - (float)ty + 1.0f;
            const float sx = 4.0f * Xt, sy = 4.0f * Yt;
#pragma unroll 2
            for (int t = tb; t <= te; t += 4) {
                const float xf = floorf(xc);
                const float yf = floorf(yc);
                const int cx = (int)xf;
                const int cy = (int)yf;
                const float fx = xc - xf;
                const float fy = yc - yf;
                const bool ok = (((unsigned)(cx - 1 - lox) < spanx) &
                                 ((unsigned)(cy - 1 - loy) < spany));
                const int a0 = max(cy * TPITCH + cx, 0);  // interval => in-bounds skin
                const float v00 = tile[a0],          v10 = tile[a0 + 1];
                const float v01 = tile[a0 + TPITCH], v11 = tile[a0 + TPITCH + 1];
                const float top = fmaf(fx, v10 - v00, v00);
                const float bot = fmaf(fx, v11 - v01, v01);
                const float smp = fmaf(fy, bot - top, top);
                acc += ok ? smp : 0.0f;
                xc += sx; yc += sy;
            }
            // reduce the 4 t-phases holding the same d (lanes xor 16, 32)
            acc += __shfl_xor(acc, 16, 64);
            acc += __shfl_xor(acc, 32, 64);
            if (ph == 0 && acc != 0.0f && d <= dhi)
                atomicAdd(sacc + sbase + d, acc);
        }
        // tile is read-only across views: no barrier needed
    }
}

// ---------------------------------------------------------------------------
// Kernel 2: pixel-driven exact adjoint (r9/r14 verbatim): LDS-staged view
// segment, 2 px/thread, weight folded, atomicAdd into out.
// ---------------------------------------------------------------------------
__global__ __launch_bounds__(256, 8)
void bwd_partial_kernel(const float* __restrict__ sacc,
                        const float* __restrict__ proj,
                        const float* __restrict__ weight,
                        float* __restrict__ out) {
    __shared__ float s_t[NV * DD];
    __shared__ float4 s_g[NV];
    const int tid = threadIdx.x;
    const int v0 = blockIdx.y * NV;
    const int b  = (int)blockIdx.x >> 7;          // 128 blocks (512 px) per image

    if (tid < NV) {
        float sn, cs;
        sincosf(view_angle(v0 + tid), &sn, &cs);
        s_g[tid] = make_float4(cs, sn, F_SIG * cs, F_SIG * sn);
    }
    {   // stage s_t = DT*sacc - proj : NV*DD/4 = 768 float4 chunks
        const int base = (b * VV + v0) << 8;
        const float4* s4 = (const float4*)(sacc + base);
        const float4* p4 = (const float4*)(proj + base);
#pragma unroll
        for (int k = 0; k < NV * (DD / 4) / 256; ++k) {
            const int i = tid + (k << 8);
            const float4 a = s4[i];
            const float4 p = p4[i];
            float4 r;
            r.x = fmaf(F_DT, a.x, -p.x);
            r.y = fmaf(F_DT, a.y, -p.y);
            r.z = fmaf(F_DT, a.z, -p.z);
            r.w = fmaf(F_DT, a.w, -p.w);
            ((float4*)s_t)[i] = r;
        }
    }
    __syncthreads();

    const int idx = ((int)blockIdx.x << 9) + tid;     // pixel 0; pixel 1 = idx+256
    const int y0 = (idx >> 8) & 255;
    const int x  = idx & 255;
    const float xw  = (float)x  * (1.0f / 128.0f) + (0.5f / 128.0f - 1.0f);
    const float yw0 = (float)y0 * (1.0f / 128.0f) + (0.5f / 128.0f - 1.0f);
    const float yw1 = yw0 + (1.0f / 128.0f);

    float acc0 = 0.0f, acc1 = 0.0f;
#pragma unroll 2
    for (int vi = 0; vi < NV; ++vi) {
        const float4 g = s_g[vi];                 // cs, sn, A=sig*cs, B=sig*sn
        const float* __restrict__ row = s_t + (vi << 8);
#pragma unroll
        for (int p = 0; p < 2; ++p) {
            const float yw = p ? yw1 : yw0;
            const float sw = fmaf(-xw, g.y, yw * g.x);
            const float tw = fmaf( xw, g.x, yw * g.y);
            const float dc = fmaf(sw, F_INV_DS, 127.5f);
            const float tc = fmaf(tw, F_INV_DS, 127.5f);
            const float d0f = floorf(dc);
            const float t0f = floorf(tc);
            const int d0 = (int)d0f;
            const float fd = dc - d0f;
            const float ft = tc - t0f;

            const float dx00 = fmaf(g.z, -ft, g.w * fd);
            const float dyn  = fmaf(g.z,  fd, g.w * ft);
            const float dx01 = dx00 + g.z;
            const float dy01 = g.w - dyn;
            const float dx10 = dx00 - g.w;
            const float dy10 = g.z - dyn;
            const float dx11 = dx01 - g.w;
            const float dy11 = dy10 + g.w;

            const float w00 = fmaxf(0.0f, 1.0f - fabsf(dx00)) * fmaxf(0.0f, 1.0f - fabsf(dyn));
            const float w01 = fmaxf(0.0f, 1.0f - fabsf(dx01)) * fmaxf(0.0f, 1.0f - fabsf(dy01));
            const float w10 = fmaxf(0.0f, 1.0f - fabsf(dx10)) * fmaxf(0.0f, 1.0f - fabsf(dy10));
            const float w11 = fmaxf(0.0f, 1.0f - fabsf(dx11)) * fmaxf(0.0f, 1.0f - fabsf(dy11));

            const float rA = row[d0];
            const float rB = row[d0 + 1];
            if (p == 0) {
                acc0 = fmaf(w00 + w01, rA, acc0);
                acc0 = fmaf(w10 + w11, rB, acc0);
            } else {
                acc1 = fmaf(w00 + w01, rA, acc1);
                acc1 = fmaf(w10 + w11, rB, acc1);
            }
        }
    }

    const float c = -weight[0] * F_DT;
    atomicAdd(out + idx, c * acc0);
    atomicAdd(out + idx + 256, c * acc1);
}

extern "C" void kernel_launch(void* const* d_in, const int* in_sizes, int n_in,
                              void* d_out, int out_size, void* d_ws, size_t ws_size,
                              hipStream_t stream) {
    const float* input  = (const float*)d_in[0];   // [nb, H, W]
    const float* proj   = (const float*)d_in[1];   // [nb, V, D]
    const float* weight = (const float*)d_in[2];   // [1]
    float* out  = (float*)d_out;                   // [nb, H, W]
    float* sacc = (float*)d_ws;                    // [nb, V, D] forward accumulator

    const int nb = in_sizes[0] / (HH * WW);        // B*C = 2
    const int npix = nb * HH * WW;

    init_kernel<<<256, 256, 0, stream>>>(input, out, sacc, npix / 4, nb * VV * DD / 4);
    fwd_tile_kernel<<<dim3(16, VV / VG, nb), 256, 0, stream>>>(input, sacc);
    bwd_partial_kernel<<<dim3(npix / 512, NSEG), 256, 0, stream>>>(sacc, proj, weight, out);
}